// Round 1
// baseline (1057.872 us; speedup 1.0000x reference)
//
#include <hip/hip_runtime.h>
#include <stdint.h>

// ---------------------------------------------------------------------------
// MoE top-2: gating (fp64 logits) -> grouped bf16 MFMA FFN -> logsumexp combine
// B=8192 D=3072 E=8 H=2048 O=512 K=2
// ---------------------------------------------------------------------------

typedef __bf16 bf16x8 __attribute__((ext_vector_type(8)));
typedef __bf16 bf16x4 __attribute__((ext_vector_type(4)));
typedef float floatx4 __attribute__((ext_vector_type(4)));

#define EPSF 2.2204460492503131e-16f

__device__ __forceinline__ void gl_lds16(const void* g, void* l) {
  __builtin_amdgcn_global_load_lds(
      (__attribute__((address_space(1))) void*)(g),
      (__attribute__((address_space(3))) void*)(l), 16, 0, 0);
}

// ---------------- init (counters zeroed every call; ws is poisoned 0xAA) ----
__global__ void k_init(int* cnt, double* imp) {
  const int t = threadIdx.x;
  if (t < 8) { cnt[t] = 0; imp[t] = 0.0; }
}

// ---------------- gating: one wave per row ---------------------------------
// fp64 accumulation so top-2 selection matches the np reference in near-ties.
__global__ __launch_bounds__(256) void k_gating(
    const float* __restrict__ x, const float* __restrict__ wg,
    int* __restrict__ cnt, int* __restrict__ lists,
    float* __restrict__ gpair, double* __restrict__ imp) {
  const int lane = threadIdx.x & 63;
  const int w = threadIdx.x >> 6;
  const int r = blockIdx.x * 4 + w;
  const float* xr = x + (size_t)r * 3072;
  double acc[8];
#pragma unroll
  for (int e = 0; e < 8; ++e) acc[e] = 0.0;
  for (int t = 0; t < 12; ++t) {
    const int d = t * 256 + lane * 4;
    const float4 xv = *(const float4*)(xr + d);
    const float* wrow = wg + (size_t)d * 8;
#pragma unroll
    for (int u = 0; u < 4; ++u) {
      const float xf = ((const float*)&xv)[u];
#pragma unroll
      for (int e = 0; e < 8; ++e)
        acc[e] += (double)xf * (double)wrow[u * 8 + e];
    }
  }
#pragma unroll
  for (int e = 0; e < 8; ++e) {
    double v = acc[e];
    v += __shfl_down(v, 32);
    v += __shfl_down(v, 16);
    v += __shfl_down(v, 8);
    v += __shfl_down(v, 4);
    v += __shfl_down(v, 2);
    v += __shfl_down(v, 1);
    acc[e] = v;
  }
  if (lane == 0) {
    int i0 = 0; double v0 = acc[0];
#pragma unroll
    for (int e = 1; e < 8; ++e) if (acc[e] > v0) { v0 = acc[e]; i0 = e; }
    int i1 = (i0 == 0) ? 1 : 0; double v1 = acc[i1];
#pragma unroll
    for (int e = 0; e < 8; ++e)
      if (e != i0 && acc[e] > v1 && e != i1) { v1 = acc[e]; i1 = e; }
    const float tt = (float)exp(v1 - v0);   // <= 1
    const float g0 = 1.0f / (1.0f + tt);
    const float g1 = tt / (1.0f + tt);
    const int p0 = atomicAdd(&cnt[i0], 1);
    lists[i0 * 8192 + p0] = r * 2;          // pair slot = 2r+k; src row = slot>>1
    const int p1 = atomicAdd(&cnt[i1], 1);
    lists[i1 * 8192 + p1] = r * 2 + 1;
    gpair[r * 2] = g0;
    gpair[r * 2 + 1] = g1;
    atomicAdd(&imp[i0], (double)g0);
    atomicAdd(&imp[i1], (double)g1);
  }
}

// ---------------- tile schedule + aux loss ---------------------------------
__global__ void k_sched_aux(const int* __restrict__ cnt, const double* __restrict__ imp,
                            int* __restrict__ sched, int* __restrict__ nslots,
                            float* __restrict__ aux_out) {
  if (threadIdx.x != 0 || blockIdx.x != 0) return;
  int ns = 0;
  for (int e = 0; e < 8; ++e) {
    const int c = cnt[e];
    const int t = (c + 127) >> 7;
    for (int i = 0; i < t; ++i) { sched[2 * ns] = e; sched[2 * ns + 1] = i << 7; ++ns; }
  }
  *nslots = ns;
  // aux = 0.01*(cv2(importance)+cv2(load)); load == cnt (all gates > 0)
  double mi = 0.0, ml = 0.0;
  for (int e = 0; e < 8; ++e) { mi += imp[e]; ml += (double)cnt[e]; }
  mi *= 0.125; ml *= 0.125;
  double vi = 0.0, vl = 0.0;
  for (int e = 0; e < 8; ++e) {
    const double di = imp[e] - mi; vi += di * di;
    const double dl = (double)cnt[e] - ml; vl += dl * dl;
  }
  vi /= 7.0; vl /= 7.0;
  aux_out[0] = (float)(0.01 * (vi / (mi * mi + 1e-10) + vl / (ml * ml + 1e-10)));
}

// ---------------- fp32 -> bf16 flat cast -----------------------------------
__global__ void k_cvt_bf16(const float* __restrict__ in, __bf16* __restrict__ out, int n4) {
  int i = blockIdx.x * blockDim.x + threadIdx.x;
  const int stride = gridDim.x * blockDim.x;
  for (; i < n4; i += stride) {
    const float4 v = ((const float4*)in)[i];
    bf16x4 o;
    o.x = (__bf16)v.x; o.y = (__bf16)v.y; o.z = (__bf16)v.z; o.w = (__bf16)v.w;
    ((bf16x4*)out)[i] = o;
  }
}

// ---------------- (E,R,C) fp32 -> (E,C,R) bf16 transpose -------------------
__global__ __launch_bounds__(256) void k_transpose_cvt(
    const float* __restrict__ in, __bf16* __restrict__ out, int R, int C) {
  __shared__ float tile[32][33];
  const int e = blockIdx.z;
  const int c0 = blockIdx.x * 32;
  const int r0 = blockIdx.y * 32;
  const float* src = in + (size_t)e * R * C;
  __bf16* dst = out + (size_t)e * R * C;
  const int tx = threadIdx.x, ty = threadIdx.y;  // (32,8)
#pragma unroll
  for (int i = 0; i < 4; ++i)
    tile[ty + i * 8][tx] = src[(size_t)(r0 + ty + i * 8) * C + (c0 + tx)];
  __syncthreads();
#pragma unroll
  for (int i = 0; i < 4; ++i)
    dst[(size_t)(c0 + ty + i * 8) * R + (r0 + tx)] = (__bf16)tile[tx][ty + i * 8];
}

// ---------------- grouped GEMM (m97 gemm_bt structure, gathered A) ---------
// MODE 0: h = relu(Xg @ W1t^T + b1)  -> bf16 h_pairs[p][0..2048)
// MODE 1: op = gpair[p] * exp(Hg @ W2t^T + b2) -> fp32 out_pairs[p][0..512)
template <int KDIM, int MODE>
__global__ __launch_bounds__(256, 2) void k_moe_gemm(
    const __bf16* __restrict__ Asrc, const __bf16* __restrict__ Ball,
    const float* __restrict__ bias, const int* __restrict__ lists,
    const int* __restrict__ cnt, const int* __restrict__ sched,
    const int* __restrict__ nslots, const float* __restrict__ gpair,
    __bf16* __restrict__ hout, float* __restrict__ oout) {
  constexpr int NDIM = (MODE == 0) ? 2048 : 512;
  const int slot = blockIdx.y;
  if (slot >= *nslots) return;
  const int e = sched[2 * slot];
  const int row0 = sched[2 * slot + 1];
  const int cnte = cnt[e];
  const int n0 = blockIdx.x * 128;

  __shared__ unsigned short As[128 * 32];  // [m][k] row-major, 8KB
  __shared__ unsigned short Bs[128 * 32];  // [n][k] row-major (B^T), 8KB

  const int tid = threadIdx.x;
  const int lane = tid & 63;
  const int wid = __builtin_amdgcn_readfirstlane(tid >> 6);
  const int wm = wid >> 1;
  const int wn = wid & 1;

  const __bf16* Be = Ball + (size_t)e * NDIM * KDIM;
  const int* liste = lists + e * 8192;
  const int acol = (lane & 3) * 8;

  // staging geometry: chunk = wid + 4p covers 16 rows; lane i -> row i/4, col (i%4)*8
  const __bf16* aptr[2];
  const __bf16* bptr[2];
#pragma unroll
  for (int p = 0; p < 2; ++p) {
    const int chunk = wid + 4 * p;
    const int lr = chunk * 16 + (lane >> 2);
    int m = row0 + lr;
    m = (m < cnte) ? m : (cnte - 1);        // clamp ragged edge (reads valid row)
    const int entry = liste[m];
    const int srow = (MODE == 0) ? (entry >> 1) : entry;
    aptr[p] = Asrc + (size_t)srow * KDIM + acol;
    bptr[p] = Be + (size_t)(n0 + lr) * KDIM + acol;
  }

  floatx4 acc[4][4];
#pragma unroll
  for (int i = 0; i < 4; ++i)
#pragma unroll
    for (int j = 0; j < 4; ++j) {
      acc[i][j].x = 0.f; acc[i][j].y = 0.f; acc[i][j].z = 0.f; acc[i][j].w = 0.f;
    }

  for (int k0 = 0; k0 < KDIM; k0 += 32) {
#pragma unroll
    for (int p = 0; p < 2; ++p) {
      gl_lds16(aptr[p] + k0, &As[(wid + 4 * p) * 512]);
      gl_lds16(bptr[p] + k0, &Bs[(wid + 4 * p) * 512]);
    }
    __syncthreads();
    bf16x8 af[4], bfr[4];
    const int rdoff = (lane & 15) * 32 + (lane >> 4) * 8;
#pragma unroll
    for (int i = 0; i < 4; ++i)
      af[i] = *(const bf16x8*)&As[(wm * 64 + i * 16) * 32 + rdoff];
#pragma unroll
    for (int j = 0; j < 4; ++j)
      bfr[j] = *(const bf16x8*)&Bs[(wn * 64 + j * 16) * 32 + rdoff];
    __syncthreads();
#pragma unroll
    for (int i = 0; i < 4; ++i)
#pragma unroll
      for (int j = 0; j < 4; ++j)
        acc[i][j] = __builtin_amdgcn_mfma_f32_16x16x32_bf16(af[i], bfr[j], acc[i][j], 0, 0, 0);
  }

  // epilogue: C/D layout col=lane&15, row=(lane>>4)*4+reg  [measured m89/m91]
  const int cq = lane >> 4;
  const int cn = lane & 15;
#pragma unroll
  for (int i = 0; i < 4; ++i) {
#pragma unroll
    for (int r = 0; r < 4; ++r) {
      const int m = row0 + wm * 64 + i * 16 + cq * 4 + r;
      if (m < cnte) {
        const int p = liste[m];
        if (MODE == 0) {
          __bf16* orow = hout + (size_t)p * 2048;
#pragma unroll
          for (int j = 0; j < 4; ++j) {
            const int n = n0 + wn * 64 + j * 16 + cn;
            float v = acc[i][j][r] + bias[e * 2048 + n];
            v = v > 0.0f ? v : 0.0f;
            orow[n] = (__bf16)v;
          }
        } else {
          float* orow = oout + (size_t)p * 512;
          const float g = gpair[p];
#pragma unroll
          for (int j = 0; j < 4; ++j) {
            const int n = n0 + wn * 64 + j * 16 + cn;
            const float v = acc[i][j][r] + bias[e * 512 + n];
            orow[n] = g * __expf(v);
          }
        }
      }
    }
  }
}

// ---------------- combine: y[r] = log(op[2r] + op[2r+1]) -------------------
__global__ __launch_bounds__(128) void k_combine(const float* __restrict__ op,
                                                 float* __restrict__ y) {
  const int r = blockIdx.x;
  const int o = threadIdx.x * 4;
  const float4 a = *(const float4*)(op + (size_t)(2 * r) * 512 + o);
  const float4 b = *(const float4*)(op + (size_t)(2 * r + 1) * 512 + o);
  float4 res;
  float s;
  s = a.x + b.x; if (s == 0.0f) s = EPSF; res.x = logf(s);
  s = a.y + b.y; if (s == 0.0f) s = EPSF; res.y = logf(s);
  s = a.z + b.z; if (s == 0.0f) s = EPSF; res.z = logf(s);
  s = a.w + b.w; if (s == 0.0f) s = EPSF; res.w = logf(s);
  *(float4*)(y + (size_t)r * 512 + o) = res;
}

// ---------------------------------------------------------------------------
extern "C" void kernel_launch(void* const* d_in, const int* in_sizes, int n_in,
                              void* d_out, int out_size, void* d_ws, size_t ws_size,
                              hipStream_t stream) {
  (void)in_sizes; (void)n_in; (void)out_size; (void)ws_size;
  const float* x  = (const float*)d_in[0];
  // d_in[1] = Cats (unused by reference)
  const float* wg = (const float*)d_in[2];
  const float* W1 = (const float*)d_in[3];
  const float* b1 = (const float*)d_in[4];
  const float* W2 = (const float*)d_in[5];
  const float* b2 = (const float*)d_in[6];
  float* y = (float*)d_out;

  // workspace carve (~269 MB)
  char* w = (char*)d_ws;
  __bf16* x_bf = (__bf16*)w; w += (size_t)8192 * 3072 * 2;        // 50.3 MB
  __bf16* w1t  = (__bf16*)w; w += (size_t)8 * 2048 * 3072 * 2;    // 100.7 MB (E,H,D)
  __bf16* w2t  = (__bf16*)w; w += (size_t)8 * 512 * 2048 * 2;     // 16.8 MB (E,O,H)
  __bf16* hp   = (__bf16*)w; w += (size_t)16384 * 2048 * 2;       // 67.1 MB pair-h
  float*  op   = (float*)w;  w += (size_t)16384 * 512 * 4;        // 33.6 MB pair-out
  int*    lists= (int*)w;    w += (size_t)8 * 8192 * 4;           // expert row lists
  float*  gpr  = (float*)w;  w += (size_t)16384 * 4;              // gate per pair
  int*    cnt  = (int*)w;    w += 64;
  double* imp  = (double*)w; w += 64;
  int*    sched= (int*)w;    w += 2 * 136 * 4;
  int*    nslots=(int*)w;    w += 64;

  hipLaunchKernelGGL(k_init, dim3(1), dim3(64), 0, stream, cnt, imp);
  hipLaunchKernelGGL(k_gating, dim3(2048), dim3(256), 0, stream, x, wg, cnt, lists, gpr, imp);
  hipLaunchKernelGGL(k_cvt_bf16, dim3(4096), dim3(256), 0, stream, x, x_bf, (8192 * 3072) / 4);
  hipLaunchKernelGGL(k_transpose_cvt, dim3(64, 96, 8), dim3(32, 8), 0, stream, W1, w1t, 3072, 2048);
  hipLaunchKernelGGL(k_transpose_cvt, dim3(16, 64, 8), dim3(32, 8), 0, stream, W2, w2t, 2048, 512);
  hipLaunchKernelGGL(k_sched_aux, dim3(1), dim3(64), 0, stream, cnt, imp, sched, nslots,
                     y + (size_t)8192 * 512);
  hipLaunchKernelGGL((k_moe_gemm<3072, 0>), dim3(16, 136), dim3(256), 0, stream,
                     x_bf, w1t, b1, lists, cnt, sched, nslots, (const float*)nullptr,
                     hp, (float*)nullptr);
  hipLaunchKernelGGL((k_moe_gemm<2048, 1>), dim3(4, 136), dim3(256), 0, stream,
                     hp, w2t, b2, lists, cnt, sched, nslots, gpr,
                     (__bf16*)nullptr, op);
  hipLaunchKernelGGL(k_combine, dim3(8192), dim3(128), 0, stream, op, y);
}

// Round 2
// 856.502 us; speedup vs baseline: 1.2351x; 1.2351x over previous
//
#include <hip/hip_runtime.h>
#include <stdint.h>

// ---------------------------------------------------------------------------
// MoE top-2: gating (fp64 logits, atomic-free) -> grouped bf16 MFMA FFN
//            -> logsumexp combine
// B=8192 D=3072 E=8 H=2048 O=512 K=2
// ---------------------------------------------------------------------------

typedef __bf16 bf16x8 __attribute__((ext_vector_type(8)));
typedef __bf16 bf16x4 __attribute__((ext_vector_type(4)));
typedef float floatx4 __attribute__((ext_vector_type(4)));

#define EPSF 2.2204460492503131e-16f

__device__ __forceinline__ void gl_lds16(const void* g, void* l) {
  __builtin_amdgcn_global_load_lds(
      (__attribute__((address_space(1))) void*)(g),
      (__attribute__((address_space(3))) void*)(l), 16, 0, 0);
}

// ---------------- gating phase A: one wave per row -------------------------
// fp64 accumulation so top-2 selection matches the np reference in near-ties.
// Fuses the x -> bf16 cast (we're already reading every element of x).
// No atomics: writes per-row expsel + gate pair only.
__global__ __launch_bounds__(256) void k_gating(
    const float* __restrict__ x, const float* __restrict__ wg,
    __bf16* __restrict__ x_bf, int* __restrict__ expsel,
    float* __restrict__ gpair) {
  const int lane = threadIdx.x & 63;
  const int w = threadIdx.x >> 6;
  const int r = blockIdx.x * 4 + w;
  const float* xr = x + (size_t)r * 3072;
  __bf16* xbr = x_bf + (size_t)r * 3072;
  double acc[8];
#pragma unroll
  for (int e = 0; e < 8; ++e) acc[e] = 0.0;
  for (int t = 0; t < 12; ++t) {
    const int d = t * 256 + lane * 4;
    const float4 xv = *(const float4*)(xr + d);
    bf16x4 xo;
    xo.x = (__bf16)xv.x; xo.y = (__bf16)xv.y;
    xo.z = (__bf16)xv.z; xo.w = (__bf16)xv.w;
    *(bf16x4*)(xbr + d) = xo;
    const float* wrow = wg + (size_t)d * 8;
#pragma unroll
    for (int u = 0; u < 4; ++u) {
      const float xf = ((const float*)&xv)[u];
#pragma unroll
      for (int e = 0; e < 8; ++e)
        acc[e] += (double)xf * (double)wrow[u * 8 + e];
    }
  }
#pragma unroll
  for (int e = 0; e < 8; ++e) {
    double v = acc[e];
    v += __shfl_down(v, 32);
    v += __shfl_down(v, 16);
    v += __shfl_down(v, 8);
    v += __shfl_down(v, 4);
    v += __shfl_down(v, 2);
    v += __shfl_down(v, 1);
    acc[e] = v;
  }
  if (lane == 0) {
    int i0 = 0; double v0 = acc[0];
#pragma unroll
    for (int e = 1; e < 8; ++e) if (acc[e] > v0) { v0 = acc[e]; i0 = e; }
    int i1 = (i0 == 0) ? 1 : 0; double v1 = acc[i1];
#pragma unroll
    for (int e = 0; e < 8; ++e)
      if (e != i0 && acc[e] > v1 && e != i1) { v1 = acc[e]; i1 = e; }
    const float tt = (float)exp(v1 - v0);   // <= 1
    const float g0 = 1.0f / (1.0f + tt);
    const float g1 = tt / (1.0f + tt);
    expsel[r] = i0 | (i1 << 4);
    gpair[r * 2] = g0;
    gpair[r * 2 + 1] = g1;
  }
}

// ---------------- gating phase B: ordered compaction per expert ------------
// One block per expert. Ballot + cross-wave prefix scan -> row-sorted lists,
// plus block-local fp64 reduction for importance. Zero global atomics.
__global__ __launch_bounds__(256) void k_build_lists(
    const int* __restrict__ expsel, const float* __restrict__ gpair,
    int* __restrict__ lists, int* __restrict__ cnt, double* __restrict__ imp) {
  const int e = blockIdx.x;
  const int tid = threadIdx.x;
  const int lane = tid & 63;
  const int w = tid >> 6;
  __shared__ int wsum[4];
  __shared__ double dsum[4];
  int base = 0;
  double gsum = 0.0;
  int* out = lists + e * 8192;
  for (int c = 0; c < 32; ++c) {          // 8192 rows / 256 threads
    const int r = c * 256 + tid;
    const int sel = expsel[r];
    const bool m0 = ((sel & 15) == e);
    const bool m1 = (((sel >> 4) & 15) == e);
    const bool m = m0 || m1;
    const int entry = 2 * r + (m1 ? 1 : 0);
    const unsigned long long mask = __ballot(m);
    const int wcount = __popcll(mask);
    const int pos = __popcll(mask & ((1ull << lane) - 1ull));
    if (lane == 0) wsum[w] = wcount;
    __syncthreads();
    int pre = base;
#pragma unroll
    for (int ww = 0; ww < 4; ++ww) if (ww < w) pre += wsum[ww];
    const int total = wsum[0] + wsum[1] + wsum[2] + wsum[3];
    if (m) {
      out[pre + pos] = entry;
      gsum += (double)gpair[entry];
    }
    base += total;
    __syncthreads();
  }
  gsum += __shfl_down(gsum, 32);
  gsum += __shfl_down(gsum, 16);
  gsum += __shfl_down(gsum, 8);
  gsum += __shfl_down(gsum, 4);
  gsum += __shfl_down(gsum, 2);
  gsum += __shfl_down(gsum, 1);
  if (lane == 0) dsum[w] = gsum;
  __syncthreads();
  if (tid == 0) {
    imp[e] = dsum[0] + dsum[1] + dsum[2] + dsum[3];
    cnt[e] = base;
  }
}

// ---------------- tile schedule + aux loss ---------------------------------
__global__ void k_sched_aux(const int* __restrict__ cnt, const double* __restrict__ imp,
                            int* __restrict__ sched, int* __restrict__ nslots,
                            float* __restrict__ aux_out) {
  if (threadIdx.x != 0 || blockIdx.x != 0) return;
  int ns = 0;
  for (int e = 0; e < 8; ++e) {
    const int c = cnt[e];
    const int t = (c + 127) >> 7;
    for (int i = 0; i < t; ++i) { sched[2 * ns] = e; sched[2 * ns + 1] = i << 7; ++ns; }
  }
  *nslots = ns;
  // aux = 0.01*(cv2(importance)+cv2(load)); load == cnt (all gates > 0)
  double mi = 0.0, ml = 0.0;
  for (int e = 0; e < 8; ++e) { mi += imp[e]; ml += (double)cnt[e]; }
  mi *= 0.125; ml *= 0.125;
  double vi = 0.0, vl = 0.0;
  for (int e = 0; e < 8; ++e) {
    const double di = imp[e] - mi; vi += di * di;
    const double dl = (double)cnt[e] - ml; vl += dl * dl;
  }
  vi /= 7.0; vl /= 7.0;
  aux_out[0] = (float)(0.01 * (vi / (mi * mi + 1e-10) + vl / (ml * ml + 1e-10)));
}

// ---------------- (E,R,C) fp32 -> (E,C,R) bf16 transpose, 64x64 tiles ------
// float4 global loads, bf16x4 stores; pad-65 LDS rows -> <=2-way conflicts.
__global__ __launch_bounds__(256) void k_transpose_cvt(
    const float* __restrict__ in, __bf16* __restrict__ out, int R, int C) {
  __shared__ float tile[64][65];
  const int e = blockIdx.z;
  const int c0 = blockIdx.x * 64;
  const int r0 = blockIdx.y * 64;
  const float* src = in + (size_t)e * R * C + (size_t)r0 * C + c0;
  __bf16* dst = out + (size_t)e * R * C + (size_t)c0 * R + r0;
  const int tx = threadIdx.x & 15;   // quad within row / quad within col
  const int ty = threadIdx.x >> 4;   // 0..15
#pragma unroll
  for (int i = 0; i < 4; ++i) {
    const int row = ty + i * 16;
    const float4 v = *(const float4*)(src + (size_t)row * C + tx * 4);
    tile[row][tx * 4 + 0] = v.x;
    tile[row][tx * 4 + 1] = v.y;
    tile[row][tx * 4 + 2] = v.z;
    tile[row][tx * 4 + 3] = v.w;
  }
  __syncthreads();
#pragma unroll
  for (int i = 0; i < 4; ++i) {
    const int cc = ty + i * 16;
    const int rr = tx * 4;
    bf16x4 o;
    o.x = (__bf16)tile[rr + 0][cc];
    o.y = (__bf16)tile[rr + 1][cc];
    o.z = (__bf16)tile[rr + 2][cc];
    o.w = (__bf16)tile[rr + 3][cc];
    *(bf16x4*)(dst + (size_t)cc * R + rr) = o;
  }
}

// ---------------- grouped GEMM (m97 gemm_bt structure, gathered A) ---------
// MODE 0: h = relu(Xg @ W1t^T + b1)  -> bf16 h_pairs[p][0..2048)
// MODE 1: op = gpair[p] * exp(Hg @ W2t^T + b2) -> fp32 out_pairs[p][0..512)
template <int KDIM, int MODE>
__global__ __launch_bounds__(256, 2) void k_moe_gemm(
    const __bf16* __restrict__ Asrc, const __bf16* __restrict__ Ball,
    const float* __restrict__ bias, const int* __restrict__ lists,
    const int* __restrict__ cnt, const int* __restrict__ sched,
    const int* __restrict__ nslots, const float* __restrict__ gpair,
    __bf16* __restrict__ hout, float* __restrict__ oout) {
  constexpr int NDIM = (MODE == 0) ? 2048 : 512;
  const int slot = blockIdx.y;
  if (slot >= *nslots) return;
  const int e = sched[2 * slot];
  const int row0 = sched[2 * slot + 1];
  const int cnte = cnt[e];
  const int n0 = blockIdx.x * 128;

  __shared__ unsigned short As[128 * 32];  // [m][k] row-major, 8KB
  __shared__ unsigned short Bs[128 * 32];  // [n][k] row-major (B^T), 8KB

  const int tid = threadIdx.x;
  const int lane = tid & 63;
  const int wid = __builtin_amdgcn_readfirstlane(tid >> 6);
  const int wm = wid >> 1;
  const int wn = wid & 1;

  const __bf16* Be = Ball + (size_t)e * NDIM * KDIM;
  const int* liste = lists + e * 8192;
  const int acol = (lane & 3) * 8;

  // staging geometry: chunk = wid + 4p covers 16 rows; lane i -> row i/4, col (i%4)*8
  const __bf16* aptr[2];
  const __bf16* bptr[2];
#pragma unroll
  for (int p = 0; p < 2; ++p) {
    const int chunk = wid + 4 * p;
    const int lr = chunk * 16 + (lane >> 2);
    int m = row0 + lr;
    m = (m < cnte) ? m : (cnte - 1);        // clamp ragged edge (reads valid row)
    const int entry = liste[m];
    const int srow = (MODE == 0) ? (entry >> 1) : entry;
    aptr[p] = Asrc + (size_t)srow * KDIM + acol;
    bptr[p] = Be + (size_t)(n0 + lr) * KDIM + acol;
  }

  floatx4 acc[4][4];
#pragma unroll
  for (int i = 0; i < 4; ++i)
#pragma unroll
    for (int j = 0; j < 4; ++j) {
      acc[i][j].x = 0.f; acc[i][j].y = 0.f; acc[i][j].z = 0.f; acc[i][j].w = 0.f;
    }

  for (int k0 = 0; k0 < KDIM; k0 += 32) {
#pragma unroll
    for (int p = 0; p < 2; ++p) {
      gl_lds16(aptr[p] + k0, &As[(wid + 4 * p) * 512]);
      gl_lds16(bptr[p] + k0, &Bs[(wid + 4 * p) * 512]);
    }
    __syncthreads();
    bf16x8 af[4], bfr[4];
    const int rdoff = (lane & 15) * 32 + (lane >> 4) * 8;
#pragma unroll
    for (int i = 0; i < 4; ++i)
      af[i] = *(const bf16x8*)&As[(wm * 64 + i * 16) * 32 + rdoff];
#pragma unroll
    for (int j = 0; j < 4; ++j)
      bfr[j] = *(const bf16x8*)&Bs[(wn * 64 + j * 16) * 32 + rdoff];
    __syncthreads();
#pragma unroll
    for (int i = 0; i < 4; ++i)
#pragma unroll
      for (int j = 0; j < 4; ++j)
        acc[i][j] = __builtin_amdgcn_mfma_f32_16x16x32_bf16(af[i], bfr[j], acc[i][j], 0, 0, 0);
  }

  // epilogue: C/D layout col=lane&15, row=(lane>>4)*4+reg  [measured m89/m91]
  const int cq = lane >> 4;
  const int cn = lane & 15;
#pragma unroll
  for (int i = 0; i < 4; ++i) {
#pragma unroll
    for (int r = 0; r < 4; ++r) {
      const int m = row0 + wm * 64 + i * 16 + cq * 4 + r;
      if (m < cnte) {
        const int p = liste[m];
        if (MODE == 0) {
          __bf16* orow = hout + (size_t)p * 2048;
#pragma unroll
          for (int j = 0; j < 4; ++j) {
            const int n = n0 + wn * 64 + j * 16 + cn;
            float v = acc[i][j][r] + bias[e * 2048 + n];
            v = v > 0.0f ? v : 0.0f;
            orow[n] = (__bf16)v;
          }
        } else {
          float* orow = oout + (size_t)p * 512;
          const float g = gpair[p];
#pragma unroll
          for (int j = 0; j < 4; ++j) {
            const int n = n0 + wn * 64 + j * 16 + cn;
            const float v = acc[i][j][r] + bias[e * 512 + n];
            orow[n] = g * __expf(v);
          }
        }
      }
    }
  }
}

// ---------------- combine: y[r] = log(op[2r] + op[2r+1]) -------------------
__global__ __launch_bounds__(128) void k_combine(const float* __restrict__ op,
                                                 float* __restrict__ y) {
  const int r = blockIdx.x;
  const int o = threadIdx.x * 4;
  const float4 a = *(const float4*)(op + (size_t)(2 * r) * 512 + o);
  const float4 b = *(const float4*)(op + (size_t)(2 * r + 1) * 512 + o);
  float4 res;
  float s;
  s = a.x + b.x; if (s == 0.0f) s = EPSF; res.x = logf(s);
  s = a.y + b.y; if (s == 0.0f) s = EPSF; res.y = logf(s);
  s = a.z + b.z; if (s == 0.0f) s = EPSF; res.z = logf(s);
  s = a.w + b.w; if (s == 0.0f) s = EPSF; res.w = logf(s);
  *(float4*)(y + (size_t)r * 512 + o) = res;
}

// ---------------------------------------------------------------------------
extern "C" void kernel_launch(void* const* d_in, const int* in_sizes, int n_in,
                              void* d_out, int out_size, void* d_ws, size_t ws_size,
                              hipStream_t stream) {
  (void)in_sizes; (void)n_in; (void)out_size; (void)ws_size;
  const float* x  = (const float*)d_in[0];
  // d_in[1] = Cats (unused by reference)
  const float* wg = (const float*)d_in[2];
  const float* W1 = (const float*)d_in[3];
  const float* b1 = (const float*)d_in[4];
  const float* W2 = (const float*)d_in[5];
  const float* b2 = (const float*)d_in[6];
  float* y = (float*)d_out;

  // workspace carve (~269 MB)
  char* w = (char*)d_ws;
  __bf16* x_bf = (__bf16*)w; w += (size_t)8192 * 3072 * 2;        // 50.3 MB
  __bf16* w1t  = (__bf16*)w; w += (size_t)8 * 2048 * 3072 * 2;    // 100.7 MB (E,H,D)
  __bf16* w2t  = (__bf16*)w; w += (size_t)8 * 512 * 2048 * 2;     // 16.8 MB (E,O,H)
  __bf16* hp   = (__bf16*)w; w += (size_t)16384 * 2048 * 2;       // 67.1 MB pair-h
  float*  op   = (float*)w;  w += (size_t)16384 * 512 * 4;        // 33.6 MB pair-out
  int*    lists= (int*)w;    w += (size_t)8 * 8192 * 4;           // expert row lists
  float*  gpr  = (float*)w;  w += (size_t)16384 * 4;              // gate per pair
  int*    expsel=(int*)w;    w += (size_t)8192 * 4;               // e0 | e1<<4 per row
  int*    cnt  = (int*)w;    w += 64;
  double* imp  = (double*)w; w += 64;
  int*    sched= (int*)w;    w += 2 * 136 * 4;
  int*    nslots=(int*)w;    w += 64;

  hipLaunchKernelGGL(k_gating, dim3(2048), dim3(256), 0, stream, x, wg, x_bf, expsel, gpr);
  hipLaunchKernelGGL(k_build_lists, dim3(8), dim3(256), 0, stream, expsel, gpr, lists, cnt, imp);
  hipLaunchKernelGGL(k_transpose_cvt, dim3(32, 48, 8), dim3(256), 0, stream, W1, w1t, 3072, 2048);
  hipLaunchKernelGGL(k_transpose_cvt, dim3(8, 32, 8), dim3(256), 0, stream, W2, w2t, 2048, 512);
  hipLaunchKernelGGL(k_sched_aux, dim3(1), dim3(64), 0, stream, cnt, imp, sched, nslots,
                     y + (size_t)8192 * 512);
  hipLaunchKernelGGL((k_moe_gemm<3072, 0>), dim3(16, 136), dim3(256), 0, stream,
                     x_bf, w1t, b1, lists, cnt, sched, nslots, (const float*)nullptr,
                     hp, (float*)nullptr);
  hipLaunchKernelGGL((k_moe_gemm<2048, 1>), dim3(4, 136), dim3(256), 0, stream,
                     hp, w2t, b2, lists, cnt, sched, nslots, gpr,
                     (__bf16*)nullptr, op);
  hipLaunchKernelGGL(k_combine, dim3(8192), dim3(128), 0, stream, op, y);
}

// Round 3
// 804.323 us; speedup vs baseline: 1.3152x; 1.0649x over previous
//
#include <hip/hip_runtime.h>
#include <stdint.h>

// ---------------------------------------------------------------------------
// MoE top-2: gating (fp64 logits, LDS-staged w_gate) -> grouped bf16 MFMA FFN
//            -> logsumexp combine
// B=8192 D=3072 E=8 H=2048 O=512 K=2
// ---------------------------------------------------------------------------

typedef __bf16 bf16x8 __attribute__((ext_vector_type(8)));
typedef __bf16 bf16x4 __attribute__((ext_vector_type(4)));
typedef float floatx4 __attribute__((ext_vector_type(4)));

#define EPSF 2.2204460492503131e-16f

__device__ __forceinline__ void gl_lds16(const void* g, void* l) {
  __builtin_amdgcn_global_load_lds(
      (__attribute__((address_space(1))) void*)(g),
      (__attribute__((address_space(3))) void*)(l), 16, 0, 0);
}

// ---------------- gating: 8 rows/block, w_gate staged in LDS ---------------
// fp64 accumulation so top-2 selection matches the np reference in near-ties.
// Lane (g = lane>>3, e = lane&7): accumulates expert e over d-chunk g.
// w_gate staged in two 48KB halves; +4-word pad per g-chunk makes the read
// bank pattern (4g + 8i + e) % 32 -> <=2-way (free, m136).
__global__ __launch_bounds__(512) void k_gating(
    const float* __restrict__ x, const float* __restrict__ wg,
    __bf16* __restrict__ x_bf, int* __restrict__ expsel,
    float* __restrict__ gpair) {
  __shared__ float wgs[12320];  // 1536*8 + 8*4 pad words = 49.3 KB
  const int tid = threadIdx.x;
  const int lane = tid & 63;
  const int w = tid >> 6;                 // wave 0..7 -> row
  const int r = blockIdx.x * 8 + w;
  const int g = lane >> 3;                // d-chunk 0..7
  const int e = lane & 7;                 // expert
  const float* xr = x + (size_t)r * 3072;
  __bf16* xbr = x_bf + (size_t)r * 3072;

  // fused cast: x row -> bf16 (coalesced float4; also warms L1 for phase B)
#pragma unroll
  for (int t = 0; t < 12; ++t) {
    const int d = t * 256 + lane * 4;
    const float4 xv = *(const float4*)(xr + d);
    bf16x4 xo;
    xo.x = (__bf16)xv.x; xo.y = (__bf16)xv.y;
    xo.z = (__bf16)xv.z; xo.w = (__bf16)xv.w;
    *(bf16x4*)(xbr + d) = xo;
  }

  double a0 = 0.0, a1 = 0.0;
  for (int h = 0; h < 2; ++h) {
    __syncthreads();  // h=1: protect previous half's reads before overwrite
    // stage half h: words w = d_local*8+e, d_local in [0,1536); pad +4/chunk
#pragma unroll
    for (int t = 0; t < 6; ++t) {
      const int wi = t * 2048 + tid * 4;        // within-half word index
      const int gg = wi / 1536;                  // source chunk (192 d's)
      const float4 v = *(const float4*)(wg + h * 12288 + wi);
      *(float4*)(wgs + wi + 4 * gg) = v;
    }
    __syncthreads();
    const float* xrg = xr + h * 1536 + g * 192;
    const float* wbase = wgs + g * 1540 + e;    // g*1536 + 4g pad
    for (int i = 0; i < 192; i += 4) {
      const float4 xv = *(const float4*)(xrg + i);
      a0 += (double)xv.x * (double)wbase[(i + 0) * 8];
      a1 += (double)xv.y * (double)wbase[(i + 1) * 8];
      a0 += (double)xv.z * (double)wbase[(i + 2) * 8];
      a1 += (double)xv.w * (double)wbase[(i + 3) * 8];
    }
  }
  double v = a0 + a1;
  v += __shfl_xor(v, 8);
  v += __shfl_xor(v, 16);
  v += __shfl_xor(v, 32);   // lanes 0..7 now hold expert 0..7 totals
  double le[8];
#pragma unroll
  for (int ee = 0; ee < 8; ++ee) le[ee] = __shfl(v, ee);
  if (lane == 0) {
    int i0 = 0; double v0 = le[0];
#pragma unroll
    for (int k = 1; k < 8; ++k) if (le[k] > v0) { v0 = le[k]; i0 = k; }
    int i1 = (i0 == 0) ? 1 : 0; double v1 = le[i1];
#pragma unroll
    for (int k = 0; k < 8; ++k)
      if (k != i0 && le[k] > v1 && k != i1) { v1 = le[k]; i1 = k; }
    const float tt = (float)exp(v1 - v0);   // <= 1
    const float g0 = 1.0f / (1.0f + tt);
    const float g1 = tt / (1.0f + tt);
    expsel[r] = i0 | (i1 << 4);
    gpair[r * 2] = g0;
    gpair[r * 2 + 1] = g1;
  }
}

// ---------------- gating phase B: ordered compaction per expert ------------
__global__ __launch_bounds__(256) void k_build_lists(
    const int* __restrict__ expsel, const float* __restrict__ gpair,
    int* __restrict__ lists, int* __restrict__ cnt, double* __restrict__ imp) {
  const int e = blockIdx.x;
  const int tid = threadIdx.x;
  const int lane = tid & 63;
  const int w = tid >> 6;
  __shared__ int wsum[4];
  __shared__ double dsum[4];
  int base = 0;
  double gsum = 0.0;
  int* out = lists + e * 8192;
  for (int c = 0; c < 32; ++c) {          // 8192 rows / 256 threads
    const int r = c * 256 + tid;
    const int sel = expsel[r];
    const bool m0 = ((sel & 15) == e);
    const bool m1 = (((sel >> 4) & 15) == e);
    const bool m = m0 || m1;
    const int entry = 2 * r + (m1 ? 1 : 0);
    const unsigned long long mask = __ballot(m);
    const int wcount = __popcll(mask);
    const int pos = __popcll(mask & ((1ull << lane) - 1ull));
    if (lane == 0) wsum[w] = wcount;
    __syncthreads();
    int pre = base;
#pragma unroll
    for (int ww = 0; ww < 4; ++ww) if (ww < w) pre += wsum[ww];
    const int total = wsum[0] + wsum[1] + wsum[2] + wsum[3];
    if (m) {
      out[pre + pos] = entry;
      gsum += (double)gpair[entry];
    }
    base += total;
    __syncthreads();
  }
  gsum += __shfl_down(gsum, 32);
  gsum += __shfl_down(gsum, 16);
  gsum += __shfl_down(gsum, 8);
  gsum += __shfl_down(gsum, 4);
  gsum += __shfl_down(gsum, 2);
  gsum += __shfl_down(gsum, 1);
  if (lane == 0) dsum[w] = gsum;
  __syncthreads();
  if (tid == 0) {
    imp[e] = dsum[0] + dsum[1] + dsum[2] + dsum[3];
    cnt[e] = base;
  }
}

// ---------------- tile schedule + aux loss ---------------------------------
__global__ void k_sched_aux(const int* __restrict__ cnt, const double* __restrict__ imp,
                            int* __restrict__ sched, int* __restrict__ nslots,
                            float* __restrict__ aux_out) {
  if (threadIdx.x != 0 || blockIdx.x != 0) return;
  int ns = 0;
  for (int e = 0; e < 8; ++e) {
    const int c = cnt[e];
    const int t = (c + 127) >> 7;
    for (int i = 0; i < t; ++i) { sched[2 * ns] = e; sched[2 * ns + 1] = i << 7; ++ns; }
  }
  *nslots = ns;
  // aux = 0.01*(cv2(importance)+cv2(load)); load == cnt (all gates > 0)
  double mi = 0.0, ml = 0.0;
  for (int e = 0; e < 8; ++e) { mi += imp[e]; ml += (double)cnt[e]; }
  mi *= 0.125; ml *= 0.125;
  double vi = 0.0, vl = 0.0;
  for (int e = 0; e < 8; ++e) {
    const double di = imp[e] - mi; vi += di * di;
    const double dl = (double)cnt[e] - ml; vl += dl * dl;
  }
  vi /= 7.0; vl /= 7.0;
  aux_out[0] = (float)(0.01 * (vi / (mi * mi + 1e-10) + vl / (ml * ml + 1e-10)));
}

// ---------------- (E,R,C) fp32 -> (E,C,R) bf16 transpose, 64x64 tiles ------
__global__ __launch_bounds__(256) void k_transpose_cvt(
    const float* __restrict__ in, __bf16* __restrict__ out, int R, int C) {
  __shared__ float tile[64][65];
  const int e = blockIdx.z;
  const int c0 = blockIdx.x * 64;
  const int r0 = blockIdx.y * 64;
  const float* src = in + (size_t)e * R * C + (size_t)r0 * C + c0;
  __bf16* dst = out + (size_t)e * R * C + (size_t)c0 * R + r0;
  const int tx = threadIdx.x & 15;
  const int ty = threadIdx.x >> 4;
#pragma unroll
  for (int i = 0; i < 4; ++i) {
    const int row = ty + i * 16;
    const float4 v = *(const float4*)(src + (size_t)row * C + tx * 4);
    tile[row][tx * 4 + 0] = v.x;
    tile[row][tx * 4 + 1] = v.y;
    tile[row][tx * 4 + 2] = v.z;
    tile[row][tx * 4 + 3] = v.w;
  }
  __syncthreads();
#pragma unroll
  for (int i = 0; i < 4; ++i) {
    const int cc = ty + i * 16;
    const int rr = tx * 4;
    bf16x4 o;
    o.x = (__bf16)tile[rr + 0][cc];
    o.y = (__bf16)tile[rr + 1][cc];
    o.z = (__bf16)tile[rr + 2][cc];
    o.w = (__bf16)tile[rr + 3][cc];
    *(bf16x4*)(dst + (size_t)cc * R + rr) = o;
  }
}

// ---------------- grouped GEMM (m97 gemm_bt structure, gathered A) ---------
// MODE 0: h = relu(Xg @ W1t^T + b1)  -> bf16 h_pairs[p][0..2048)
// MODE 1: op = gpair[p] * exp(Hg @ W2t^T + b2) -> fp32 out_pairs[p][0..512)
template <int KDIM, int MODE>
__global__ __launch_bounds__(256, 2) void k_moe_gemm(
    const __bf16* __restrict__ Asrc, const __bf16* __restrict__ Ball,
    const float* __restrict__ bias, const int* __restrict__ lists,
    const int* __restrict__ cnt, const int* __restrict__ sched,
    const int* __restrict__ nslots, const float* __restrict__ gpair,
    __bf16* __restrict__ hout, float* __restrict__ oout) {
  constexpr int NDIM = (MODE == 0) ? 2048 : 512;
  const int slot = blockIdx.y;
  if (slot >= *nslots) return;
  const int e = sched[2 * slot];
  const int row0 = sched[2 * slot + 1];
  const int cnte = cnt[e];
  const int n0 = blockIdx.x * 128;

  __shared__ unsigned short As[128 * 32];  // [m][k] row-major, 8KB
  __shared__ unsigned short Bs[128 * 32];  // [n][k] row-major (B^T), 8KB

  const int tid = threadIdx.x;
  const int lane = tid & 63;
  const int wid = __builtin_amdgcn_readfirstlane(tid >> 6);
  const int wm = wid >> 1;
  const int wn = wid & 1;

  const __bf16* Be = Ball + (size_t)e * NDIM * KDIM;
  const int* liste = lists + e * 8192;
  const int acol = (lane & 3) * 8;

  const __bf16* aptr[2];
  const __bf16* bptr[2];
#pragma unroll
  for (int p = 0; p < 2; ++p) {
    const int chunk = wid + 4 * p;
    const int lr = chunk * 16 + (lane >> 2);
    int m = row0 + lr;
    m = (m < cnte) ? m : (cnte - 1);        // clamp ragged edge
    const int entry = liste[m];
    const int srow = (MODE == 0) ? (entry >> 1) : entry;
    aptr[p] = Asrc + (size_t)srow * KDIM + acol;
    bptr[p] = Be + (size_t)(n0 + lr) * KDIM + acol;
  }

  floatx4 acc[4][4];
#pragma unroll
  for (int i = 0; i < 4; ++i)
#pragma unroll
    for (int j = 0; j < 4; ++j) {
      acc[i][j].x = 0.f; acc[i][j].y = 0.f; acc[i][j].z = 0.f; acc[i][j].w = 0.f;
    }

  for (int k0 = 0; k0 < KDIM; k0 += 32) {
#pragma unroll
    for (int p = 0; p < 2; ++p) {
      gl_lds16(aptr[p] + k0, &As[(wid + 4 * p) * 512]);
      gl_lds16(bptr[p] + k0, &Bs[(wid + 4 * p) * 512]);
    }
    __syncthreads();
    bf16x8 af[4], bfr[4];
    const int rdoff = (lane & 15) * 32 + (lane >> 4) * 8;
#pragma unroll
    for (int i = 0; i < 4; ++i)
      af[i] = *(const bf16x8*)&As[(wm * 64 + i * 16) * 32 + rdoff];
#pragma unroll
    for (int j = 0; j < 4; ++j)
      bfr[j] = *(const bf16x8*)&Bs[(wn * 64 + j * 16) * 32 + rdoff];
    __syncthreads();
#pragma unroll
    for (int i = 0; i < 4; ++i)
#pragma unroll
      for (int j = 0; j < 4; ++j)
        acc[i][j] = __builtin_amdgcn_mfma_f32_16x16x32_bf16(af[i], bfr[j], acc[i][j], 0, 0, 0);
  }

  // epilogue: C/D layout col=lane&15, row=(lane>>4)*4+reg  [measured m89/m91]
  const int cq = lane >> 4;
  const int cn = lane & 15;
#pragma unroll
  for (int i = 0; i < 4; ++i) {
#pragma unroll
    for (int r = 0; r < 4; ++r) {
      const int m = row0 + wm * 64 + i * 16 + cq * 4 + r;
      if (m < cnte) {
        const int p = liste[m];
        if (MODE == 0) {
          __bf16* orow = hout + (size_t)p * 2048;
#pragma unroll
          for (int j = 0; j < 4; ++j) {
            const int n = n0 + wn * 64 + j * 16 + cn;
            float v = acc[i][j][r] + bias[e * 2048 + n];
            v = v > 0.0f ? v : 0.0f;
            orow[n] = (__bf16)v;
          }
        } else {
          float* orow = oout + (size_t)p * 512;
          const float g = gpair[p];
#pragma unroll
          for (int j = 0; j < 4; ++j) {
            const int n = n0 + wn * 64 + j * 16 + cn;
            const float v = acc[i][j][r] + bias[e * 512 + n];
            orow[n] = g * __expf(v);
          }
        }
      }
    }
  }
}

// ---------------- combine: y[r] = log(op[2r] + op[2r+1]) -------------------
__global__ __launch_bounds__(128) void k_combine(const float* __restrict__ op,
                                                 float* __restrict__ y) {
  const int r = blockIdx.x;
  const int o = threadIdx.x * 4;
  const float4 a = *(const float4*)(op + (size_t)(2 * r) * 512 + o);
  const float4 b = *(const float4*)(op + (size_t)(2 * r + 1) * 512 + o);
  float4 res;
  float s;
  s = a.x + b.x; if (s == 0.0f) s = EPSF; res.x = logf(s);
  s = a.y + b.y; if (s == 0.0f) s = EPSF; res.y = logf(s);
  s = a.z + b.z; if (s == 0.0f) s = EPSF; res.z = logf(s);
  s = a.w + b.w; if (s == 0.0f) s = EPSF; res.w = logf(s);
  *(float4*)(y + (size_t)r * 512 + o) = res;
}

// ---------------------------------------------------------------------------
extern "C" void kernel_launch(void* const* d_in, const int* in_sizes, int n_in,
                              void* d_out, int out_size, void* d_ws, size_t ws_size,
                              hipStream_t stream) {
  (void)in_sizes; (void)n_in; (void)out_size; (void)ws_size;
  const float* x  = (const float*)d_in[0];
  // d_in[1] = Cats (unused by reference)
  const float* wg = (const float*)d_in[2];
  const float* W1 = (const float*)d_in[3];
  const float* b1 = (const float*)d_in[4];
  const float* W2 = (const float*)d_in[5];
  const float* b2 = (const float*)d_in[6];
  float* y = (float*)d_out;

  // workspace carve (~269 MB)
  char* w = (char*)d_ws;
  __bf16* x_bf = (__bf16*)w; w += (size_t)8192 * 3072 * 2;        // 50.3 MB
  __bf16* w1t  = (__bf16*)w; w += (size_t)8 * 2048 * 3072 * 2;    // 100.7 MB (E,H,D)
  __bf16* w2t  = (__bf16*)w; w += (size_t)8 * 512 * 2048 * 2;     // 16.8 MB (E,O,H)
  __bf16* hp   = (__bf16*)w; w += (size_t)16384 * 2048 * 2;       // 67.1 MB pair-h
  float*  op   = (float*)w;  w += (size_t)16384 * 512 * 4;        // 33.6 MB pair-out
  int*    lists= (int*)w;    w += (size_t)8 * 8192 * 4;           // expert row lists
  float*  gpr  = (float*)w;  w += (size_t)16384 * 4;              // gate per pair
  int*    expsel=(int*)w;    w += (size_t)8192 * 4;               // e0 | e1<<4 per row
  int*    cnt  = (int*)w;    w += 64;
  double* imp  = (double*)w; w += 64;
  int*    sched= (int*)w;    w += 2 * 136 * 4;
  int*    nslots=(int*)w;    w += 64;

  hipLaunchKernelGGL(k_gating, dim3(1024), dim3(512), 0, stream, x, wg, x_bf, expsel, gpr);
  hipLaunchKernelGGL(k_build_lists, dim3(8), dim3(256), 0, stream, expsel, gpr, lists, cnt, imp);
  hipLaunchKernelGGL(k_transpose_cvt, dim3(32, 48, 8), dim3(256), 0, stream, W1, w1t, 3072, 2048);
  hipLaunchKernelGGL(k_transpose_cvt, dim3(8, 32, 8), dim3(256), 0, stream, W2, w2t, 2048, 512);
  hipLaunchKernelGGL(k_sched_aux, dim3(1), dim3(64), 0, stream, cnt, imp, sched, nslots,
                     y + (size_t)8192 * 512);
  hipLaunchKernelGGL((k_moe_gemm<3072, 0>), dim3(16, 136), dim3(256), 0, stream,
                     x_bf, w1t, b1, lists, cnt, sched, nslots, (const float*)nullptr,
                     hp, (float*)nullptr);
  hipLaunchKernelGGL((k_moe_gemm<2048, 1>), dim3(4, 136), dim3(256), 0, stream,
                     hp, w2t, b2, lists, cnt, sched, nslots, gpr,
                     (__bf16*)nullptr, op);
  hipLaunchKernelGGL(k_combine, dim3(8192), dim3(128), 0, stream, op, y);
}